// Round 19
// baseline (115.776 us; speedup 1.0000x reference)
//
#include <hip/hip_runtime.h>
#include <hip/hip_bf16.h>
#include <cstdint>

#define N_NODES 50000
#define N_EDGES 800000
#define D 96
#define NEG_SLOPE 0.2f
#define R1ROWS 16    // 50000 = 3125 * 16 exactly -> no tail guards
#define BUCKET 64    // max in-degree slack: Poisson(16) tail past 64 ~ 1e-19/node
#define NXCD 8
#define DST_PER_PART (N_NODES / NXCD)   // 6250 exactly

// K1: LDS GEMM, 16 rows/block, block (96,4)=384 threads. Stores bf16 h ONLY.
__global__ __launch_bounds__(384) void k1_gemm(
    const float* __restrict__ x, const float* __restrict__ W,
    __hip_bfloat16* __restrict__ hb) {
    __shared__ float Ws[D][D];      // [k][col] — native W layout
    __shared__ float xs[R1ROWS][D]; // [row][k]
    const int tx = threadIdx.x, ty = threadIdx.y;
    const int t = ty * 96 + tx;     // 0..383
    const size_t row0 = (size_t)blockIdx.x * R1ROWS;

    {   // stage W (2304 float4) and x tile (384 float4), fully coalesced
        const float4* W4 = (const float4*)W;
        float4* Ws4 = (float4*)Ws;
#pragma unroll
        for (int i = 0; i < 6; ++i) Ws4[t + 384 * i] = W4[t + 384 * i];
        const float4* x4 = (const float4*)(x + row0 * D);
        ((float4*)xs)[t] = x4[t];
    }
    __syncthreads();

    float acc0 = 0.f, acc1 = 0.f, acc2 = 0.f, acc3 = 0.f;
#pragma unroll
    for (int k = 0; k < D; k += 4) {
        float4 xa = *(const float4*)&xs[ty][k];
        float4 xb = *(const float4*)&xs[ty + 4][k];
        float4 xc = *(const float4*)&xs[ty + 8][k];
        float4 xd = *(const float4*)&xs[ty + 12][k];
        float w0 = Ws[k][tx], w1 = Ws[k + 1][tx], w2 = Ws[k + 2][tx], w3 = Ws[k + 3][tx];
        acc0 += xa.x * w0 + xa.y * w1 + xa.z * w2 + xa.w * w3;
        acc1 += xb.x * w0 + xb.y * w1 + xb.z * w2 + xb.w * w3;
        acc2 += xc.x * w0 + xc.y * w1 + xc.z * w2 + xc.w * w3;
        acc3 += xd.x * w0 + xd.y * w1 + xd.z * w2 + xd.w * w3;
    }
    hb[(row0 + ty     ) * D + tx] = __float2bfloat16(acc0);
    hb[(row0 + ty + 4 ) * D + tx] = __float2bfloat16(acc1);
    hb[(row0 + ty + 8 ) * D + tx] = __float2bfloat16(acc2);
    hb[(row0 + ty + 12) * D + tx] = __float2bfloat16(acc3);
}

// K1b: a_src/a_dst dots from bf16 h — one wave per row, shuffle-reduce.
// Also zeroes cnt[row] (no separate memset dispatch).
__global__ __launch_bounds__(256) void k1b_att(
    const __hip_bfloat16* __restrict__ hb, const float* __restrict__ att_src,
    const float* __restrict__ att_dst, float* __restrict__ a_src,
    float* __restrict__ a_dst, int* __restrict__ cnt) {
    const int lane = threadIdx.x & 63;
    const int row = (blockIdx.x * 256 + threadIdx.x) >> 6;
    if (row >= N_NODES) return;
    float s = 0.f, d = 0.f;
    if (lane < 48) {
        uint hv = ((const uint*)hb)[(size_t)row * 48 + lane];  // 2 bf16 features
        float h0 = __uint_as_float(hv << 16);
        float h1 = __uint_as_float(hv & 0xffff0000u);
        float2 as = *(const float2*)(att_src + lane * 2);
        float2 ad = *(const float2*)(att_dst + lane * 2);
        s = h0 * as.x + h1 * as.y;
        d = h0 * ad.x + h1 * ad.y;
    }
#pragma unroll
    for (int off = 32; off >= 1; off >>= 1) {
        s += __shfl_down(s, off);
        d += __shfl_down(d, off);
    }
    if (lane == 0) { a_src[row] = s; a_dst[row] = d; cnt[row] = 0; }
}

// Single-pass index bucketing, XCD-partitioned by dst range. No attention
// math here anymore (w moved to k_gather, in f32): just a 2B src store.
__global__ void k_bucket(const int* __restrict__ ei, int* __restrict__ cnt,
                         ushort* __restrict__ bkt) {
    const int part = blockIdx.x & (NXCD - 1);
    const int e = (blockIdx.x >> 3) * 256 + threadIdx.x;
    if (e >= N_EDGES) return;
    int d = ei[N_EDGES + e];
    int lo = part * DST_PER_PART;
    if (d < lo || d >= lo + DST_PER_PART) return;
    int pos = atomicAdd(&cnt[d], 1);
    if (pos < BUCKET) bkt[(size_t)d * BUCKET + pos] = (ushort)ei[e];
}

// One WAVE per node, zero barriers. Node mapping XCD-partitioned to match
// k_bucket. Lanes 0..47 own 2 features; lanes 48..63 duplicate lanes
// 32..47's addresses (ll = lane<48 ? lane : lane-16 — NOT lane&47, which
// corrupts lanes 16..31). Per edge: 2B src from bucket, 4B a_src gather
// (L2-resident) + 4B h gather in parallel, f32 exp per lane.
__global__ __launch_bounds__(256) void k_gather(
    const int* __restrict__ cnt, const ushort* __restrict__ bkt,
    const float* __restrict__ a_src, const float* __restrict__ a_dst,
    const __hip_bfloat16* __restrict__ hb, const float* __restrict__ bias,
    float* __restrict__ out) {
    const uint lane = threadIdx.x & 63;
    const uint ll = (lane < 48u) ? lane : (lane - 16u);  // 48..63 -> 32..47
    const int part = blockIdx.x & (NXCD - 1);
    const int l = (int)((blockIdx.x >> 3) * 4 + (threadIdx.x >> 6));
    if (l >= DST_PER_PART) return;
    const int node = part * DST_PER_PART + l;
    const uint* __restrict__ hbu = (const uint*)hb;  // one uint = 2 bf16 features
    const ushort* __restrict__ bucket = bkt + (size_t)node * BUCKET;
    const int cn = min(cnt[node], BUCKET);
    const float adst = a_dst[node];

    // self-loop
    float es = a_src[node] + adst;
    es = es > 0.f ? es : NEG_SLOPE * es;
    float wself = __expf(es);
    uint pself = hbu[(uint)node * 48u + ll];
    float acc0 = __uint_as_float(pself << 16) * wself;
    float acc1 = __uint_as_float(pself & 0xffff0000u) * wself;
    float wsum = wself;

    int k = 0;
    for (; k + 15 < cn; k += 16) {
        uint4 b0 = *(const uint4*)&bucket[k];       // 8 src indices
        uint4 b1 = *(const uint4*)&bucket[k + 8];   // 8 src indices
        uint s[16];
        s[0] = b0.x & 0xFFFFu;  s[1] = b0.x >> 16;
        s[2] = b0.y & 0xFFFFu;  s[3] = b0.y >> 16;
        s[4] = b0.z & 0xFFFFu;  s[5] = b0.z >> 16;
        s[6] = b0.w & 0xFFFFu;  s[7] = b0.w >> 16;
        s[8] = b1.x & 0xFFFFu;  s[9] = b1.x >> 16;
        s[10] = b1.y & 0xFFFFu; s[11] = b1.y >> 16;
        s[12] = b1.z & 0xFFFFu; s[13] = b1.z >> 16;
        s[14] = b1.w & 0xFFFFu; s[15] = b1.w >> 16;
        uint p[16]; float a[16];
#pragma unroll
        for (int j = 0; j < 16; ++j) p[j] = hbu[s[j] * 48u + ll];
#pragma unroll
        for (int j = 0; j < 16; ++j) a[j] = a_src[s[j]];
#pragma unroll
        for (int j = 0; j < 16; ++j) {
            float v = a[j] + adst;
            v = v > 0.f ? v : NEG_SLOPE * v;
            float w = __expf(v);
            acc0 += __uint_as_float(p[j] << 16) * w;
            acc1 += __uint_as_float(p[j] & 0xffff0000u) * w;
            wsum += w;
        }
    }
    if (k + 7 < cn) {
        uint4 b0 = *(const uint4*)&bucket[k];
        uint s[8];
        s[0] = b0.x & 0xFFFFu; s[1] = b0.x >> 16;
        s[2] = b0.y & 0xFFFFu; s[3] = b0.y >> 16;
        s[4] = b0.z & 0xFFFFu; s[5] = b0.z >> 16;
        s[6] = b0.w & 0xFFFFu; s[7] = b0.w >> 16;
        uint p[8]; float a[8];
#pragma unroll
        for (int j = 0; j < 8; ++j) p[j] = hbu[s[j] * 48u + ll];
#pragma unroll
        for (int j = 0; j < 8; ++j) a[j] = a_src[s[j]];
#pragma unroll
        for (int j = 0; j < 8; ++j) {
            float v = a[j] + adst;
            v = v > 0.f ? v : NEG_SLOPE * v;
            float w = __expf(v);
            acc0 += __uint_as_float(p[j] << 16) * w;
            acc1 += __uint_as_float(p[j] & 0xffff0000u) * w;
            wsum += w;
        }
        k += 8;
    }
    if (k + 3 < cn) {
        uint2 b0 = *(const uint2*)&bucket[k];
        uint s[4];
        s[0] = b0.x & 0xFFFFu; s[1] = b0.x >> 16;
        s[2] = b0.y & 0xFFFFu; s[3] = b0.y >> 16;
        uint p[4]; float a[4];
#pragma unroll
        for (int j = 0; j < 4; ++j) p[j] = hbu[s[j] * 48u + ll];
#pragma unroll
        for (int j = 0; j < 4; ++j) a[j] = a_src[s[j]];
#pragma unroll
        for (int j = 0; j < 4; ++j) {
            float v = a[j] + adst;
            v = v > 0.f ? v : NEG_SLOPE * v;
            float w = __expf(v);
            acc0 += __uint_as_float(p[j] << 16) * w;
            acc1 += __uint_as_float(p[j] & 0xffff0000u) * w;
            wsum += w;
        }
        k += 4;
    }
    for (; k < cn; ++k) {
        uint s0 = bucket[k];
        uint p0 = hbu[s0 * 48u + ll];
        float v = a_src[s0] + adst;
        v = v > 0.f ? v : NEG_SLOPE * v;
        float w0 = __expf(v);
        acc0 += __uint_as_float(p0 << 16) * w0;
        acc1 += __uint_as_float(p0 & 0xffff0000u) * w0;
        wsum += w0;
    }

    if (lane < 48) {
        float inv = 1.f / (wsum + 1e-16f);
        float2 bv = *(const float2*)(bias + lane * 2);
        float2 o;
        o.x = tanhf(acc0 * inv + bv.x);
        o.y = tanhf(acc1 * inv + bv.y);
        *(float2*)(out + (size_t)node * D + lane * 2) = o;
    }
}

extern "C" void kernel_launch(void* const* d_in, const int* in_sizes, int n_in,
                              void* d_out, int out_size, void* d_ws, size_t ws_size,
                              hipStream_t stream) {
    const float* x       = (const float*)d_in[0];
    const float* W       = (const float*)d_in[1];
    const float* att_src = (const float*)d_in[2];
    const float* att_dst = (const float*)d_in[3];
    const float* bias    = (const float*)d_in[4];
    const int*   ei      = (const int*)d_in[5];
    float* out = (float*)d_out;

    char* ws = (char*)d_ws;
    __hip_bfloat16* hb = (__hip_bfloat16*)ws; ws += (size_t)N_NODES * D * 2;
    float*  a_src = (float*)ws;  ws += (size_t)N_NODES * 4;
    float*  a_dst = (float*)ws;  ws += (size_t)N_NODES * 4;
    int*    cnt   = (int*)ws;    ws += (size_t)N_NODES * 4;
    ushort* bkt   = (ushort*)ws; ws += (size_t)N_NODES * BUCKET * 2;

    k1_gemm<<<N_NODES / R1ROWS, dim3(96, 4), 0, stream>>>(x, W, hb);
    k1b_att<<<(N_NODES * 64 + 255) / 256, 256, 0, stream>>>(hb, att_src, att_dst, a_src, a_dst, cnt);
    k_bucket<<<((N_EDGES + 255) / 256) * NXCD, 256, 0, stream>>>(ei, cnt, bkt);
    k_gather<<<((DST_PER_PART + 3) / 4) * NXCD, 256, 0, stream>>>(
        cnt, bkt, a_src, a_dst, hb, bias, out);
}

// Round 20
// 114.003 us; speedup vs baseline: 1.0156x; 1.0156x over previous
//
#include <hip/hip_runtime.h>
#include <hip/hip_bf16.h>
#include <cstdint>

#define N_NODES 50000
#define N_EDGES 800000
#define D 96
#define NEG_SLOPE 0.2f
#define R1ROWS 16    // 50000 = 3125 * 16 exactly -> no tail guards
#define BUCKET 64    // max in-degree slack: Poisson(16) tail past 64 ~ 1e-19/node
#define NXCD 8
#define DST_PER_PART (N_NODES / NXCD)   // 6250 exactly

// K1: LDS GEMM, 16 rows/block, block (96,4)=384 threads. Stores bf16 h ONLY.
// (Round-14 lesson, thrice-confirmed: NO fused serial/reduction phases here.)
__global__ __launch_bounds__(384) void k1_gemm(
    const float* __restrict__ x, const float* __restrict__ W,
    __hip_bfloat16* __restrict__ hb) {
    __shared__ float Ws[D][D];      // [k][col] — native W layout
    __shared__ float xs[R1ROWS][D]; // [row][k]
    const int tx = threadIdx.x, ty = threadIdx.y;
    const int t = ty * 96 + tx;     // 0..383
    const size_t row0 = (size_t)blockIdx.x * R1ROWS;

    {   // stage W (2304 float4) and x tile (384 float4), fully coalesced
        const float4* W4 = (const float4*)W;
        float4* Ws4 = (float4*)Ws;
#pragma unroll
        for (int i = 0; i < 6; ++i) Ws4[t + 384 * i] = W4[t + 384 * i];
        const float4* x4 = (const float4*)(x + row0 * D);
        ((float4*)xs)[t] = x4[t];
    }
    __syncthreads();

    float acc0 = 0.f, acc1 = 0.f, acc2 = 0.f, acc3 = 0.f;
#pragma unroll
    for (int k = 0; k < D; k += 4) {
        float4 xa = *(const float4*)&xs[ty][k];
        float4 xb = *(const float4*)&xs[ty + 4][k];
        float4 xc = *(const float4*)&xs[ty + 8][k];
        float4 xd = *(const float4*)&xs[ty + 12][k];
        float w0 = Ws[k][tx], w1 = Ws[k + 1][tx], w2 = Ws[k + 2][tx], w3 = Ws[k + 3][tx];
        acc0 += xa.x * w0 + xa.y * w1 + xa.z * w2 + xa.w * w3;
        acc1 += xb.x * w0 + xb.y * w1 + xb.z * w2 + xb.w * w3;
        acc2 += xc.x * w0 + xc.y * w1 + xc.z * w2 + xc.w * w3;
        acc3 += xd.x * w0 + xd.y * w1 + xd.z * w2 + xd.w * w3;
    }
    hb[(row0 + ty     ) * D + tx] = __float2bfloat16(acc0);
    hb[(row0 + ty + 4 ) * D + tx] = __float2bfloat16(acc1);
    hb[(row0 + ty + 8 ) * D + tx] = __float2bfloat16(acc2);
    hb[(row0 + ty + 12) * D + tx] = __float2bfloat16(acc3);
}

// K1b: a_src/a_dst dots from bf16 h — one wave per row, shuffle-reduce.
// Also zeroes cnt[row] (no separate memset dispatch).
__global__ __launch_bounds__(256) void k1b_att(
    const __hip_bfloat16* __restrict__ hb, const float* __restrict__ att_src,
    const float* __restrict__ att_dst, float* __restrict__ a_src,
    float* __restrict__ a_dst, int* __restrict__ cnt) {
    const int lane = threadIdx.x & 63;
    const int row = (blockIdx.x * 256 + threadIdx.x) >> 6;
    if (row >= N_NODES) return;
    float s = 0.f, d = 0.f;
    if (lane < 48) {
        uint hv = ((const uint*)hb)[(size_t)row * 48 + lane];  // 2 bf16 features
        float h0 = __uint_as_float(hv << 16);           // even feature 2*lane
        float h1 = __uint_as_float(hv & 0xffff0000u);   // odd  feature 2*lane+1
        float2 as = *(const float2*)(att_src + lane * 2);
        float2 ad = *(const float2*)(att_dst + lane * 2);
        s = h0 * as.x + h1 * as.y;
        d = h0 * ad.x + h1 * ad.y;
    }
#pragma unroll
    for (int off = 32; off >= 1; off >>= 1) {
        s += __shfl_down(s, off);
        d += __shfl_down(d, off);
    }
    if (lane == 0) { a_src[row] = s; a_dst[row] = d; cnt[row] = 0; }
}

// Single-pass CSR-bucket build, XCD-partitioned by dst range: each
// bucket/cnt line is written from ONE XCD (kills cross-XCD line ping-pong;
// the 8x ei re-read is the measured-cheaper trade, round 8/9).
__global__ void k_bucket(const int* __restrict__ ei,
                         const float* __restrict__ a_src, const float* __restrict__ a_dst,
                         int* __restrict__ cnt, uint* __restrict__ bkt) {
    const int part = blockIdx.x & (NXCD - 1);
    const int e = (blockIdx.x >> 3) * 256 + threadIdx.x;
    if (e >= N_EDGES) return;
    int d = ei[N_EDGES + e];
    int lo = part * DST_PER_PART;
    if (d < lo || d >= lo + DST_PER_PART) return;
    int s = ei[e];
    float v = a_src[s] + a_dst[d];
    v = v > 0.f ? v : NEG_SLOPE * v;
    float w = __expf(v);
    uint u = __float_as_uint(w);
    uint wb = (u + 0x7FFFu + ((u >> 16) & 1u)) & 0xFFFF0000u;  // RNE bf16, kept in high half
    uint pk = wb | (uint)s;                                    // src < 65536
    int pos = atomicAdd(&cnt[d], 1);
    if (pos < BUCKET) bkt[(size_t)d * BUCKET + pos] = pk;
}

// One WAVE per node, zero barriers. Node mapping XCD-partitioned to match
// k_bucket. Lanes 0..47 own 2 features (one bf16x2 = 4B load per edge);
// lanes 48..63 duplicate lanes 32..47's addresses so a 192B (3-line) hb row
// never drags in a 4th line. NOTE: the remap must be lane<48 ? lane :
// lane-16 — `lane & 47` clears bit 4 and corrupts lanes 16..31 (round-16/17
// bug, absmax 1.9).
__global__ __launch_bounds__(256) void k_gather(
    const int* __restrict__ cnt, const uint* __restrict__ bkt,
    const float* __restrict__ a_src, const float* __restrict__ a_dst,
    const __hip_bfloat16* __restrict__ hb, const float* __restrict__ bias,
    float* __restrict__ out) {
    const uint lane = threadIdx.x & 63;
    const uint ll = (lane < 48u) ? lane : (lane - 16u);  // 48..63 -> 32..47
    const int part = blockIdx.x & (NXCD - 1);
    const int l = (int)((blockIdx.x >> 3) * 4 + (threadIdx.x >> 6));
    if (l >= DST_PER_PART) return;
    const int node = part * DST_PER_PART + l;
    const uint* __restrict__ hbu = (const uint*)hb;  // one uint = 2 bf16 features
    const uint* __restrict__ bucket = bkt + (size_t)node * BUCKET;
    const int cn = min(cnt[node], BUCKET);

    // self-loop
    float es = a_src[node] + a_dst[node];
    es = es > 0.f ? es : NEG_SLOPE * es;
    float wself = __expf(es);
    uint pself = hbu[(uint)node * 48u + ll];
    float acc0 = __uint_as_float(pself << 16) * wself;
    float acc1 = __uint_as_float(pself & 0xffff0000u) * wself;
    float wsum = wself;

    int k = 0;
    for (; k + 15 < cn; k += 16) {
        uint b[16];
        *(uint4*)&b[0]  = *(const uint4*)&bucket[k];
        *(uint4*)&b[4]  = *(const uint4*)&bucket[k + 4];
        *(uint4*)&b[8]  = *(const uint4*)&bucket[k + 8];
        *(uint4*)&b[12] = *(const uint4*)&bucket[k + 12];
        uint p[16];
#pragma unroll
        for (int j = 0; j < 16; ++j) p[j] = hbu[(b[j] & 0xFFFFu) * 48u + ll];
#pragma unroll
        for (int j = 0; j < 16; ++j) {
            float w = __uint_as_float(b[j] & 0xFFFF0000u);
            acc0 += __uint_as_float(p[j] << 16) * w;
            acc1 += __uint_as_float(p[j] & 0xffff0000u) * w;
            wsum += w;
        }
    }
    if (k + 7 < cn) {
        uint b[8];
        *(uint4*)&b[0] = *(const uint4*)&bucket[k];
        *(uint4*)&b[4] = *(const uint4*)&bucket[k + 4];
        uint p[8];
#pragma unroll
        for (int j = 0; j < 8; ++j) p[j] = hbu[(b[j] & 0xFFFFu) * 48u + ll];
#pragma unroll
        for (int j = 0; j < 8; ++j) {
            float w = __uint_as_float(b[j] & 0xFFFF0000u);
            acc0 += __uint_as_float(p[j] << 16) * w;
            acc1 += __uint_as_float(p[j] & 0xffff0000u) * w;
            wsum += w;
        }
        k += 8;
    }
    if (k + 3 < cn) {
        uint b[4];
        *(uint4*)&b[0] = *(const uint4*)&bucket[k];
        uint p[4];
#pragma unroll
        for (int j = 0; j < 4; ++j) p[j] = hbu[(b[j] & 0xFFFFu) * 48u + ll];
#pragma unroll
        for (int j = 0; j < 4; ++j) {
            float w = __uint_as_float(b[j] & 0xFFFF0000u);
            acc0 += __uint_as_float(p[j] << 16) * w;
            acc1 += __uint_as_float(p[j] & 0xffff0000u) * w;
            wsum += w;
        }
        k += 4;
    }
    for (; k < cn; ++k) {
        uint e0 = bucket[k];
        uint p0 = hbu[(e0 & 0xFFFFu) * 48u + ll];
        float w0 = __uint_as_float(e0 & 0xFFFF0000u);
        acc0 += __uint_as_float(p0 << 16) * w0;
        acc1 += __uint_as_float(p0 & 0xffff0000u) * w0;
        wsum += w0;
    }

    if (lane < 48) {
        float inv = 1.f / (wsum + 1e-16f);
        float2 bv = *(const float2*)(bias + lane * 2);
        float2 o;
        o.x = tanhf(acc0 * inv + bv.x);
        o.y = tanhf(acc1 * inv + bv.y);
        *(float2*)(out + (size_t)node * D + lane * 2) = o;
    }
}

extern "C" void kernel_launch(void* const* d_in, const int* in_sizes, int n_in,
                              void* d_out, int out_size, void* d_ws, size_t ws_size,
                              hipStream_t stream) {
    const float* x       = (const float*)d_in[0];
    const float* W       = (const float*)d_in[1];
    const float* att_src = (const float*)d_in[2];
    const float* att_dst = (const float*)d_in[3];
    const float* bias    = (const float*)d_in[4];
    const int*   ei      = (const int*)d_in[5];
    float* out = (float*)d_out;

    char* ws = (char*)d_ws;
    __hip_bfloat16* hb = (__hip_bfloat16*)ws; ws += (size_t)N_NODES * D * 2;
    float* a_src  = (float*)ws; ws += (size_t)N_NODES * 4;
    float* a_dst  = (float*)ws; ws += (size_t)N_NODES * 4;
    int*   cnt    = (int*)ws;   ws += (size_t)N_NODES * 4;
    uint*  bkt    = (uint*)ws;  ws += (size_t)N_NODES * BUCKET * 4;

    k1_gemm<<<N_NODES / R1ROWS, dim3(96, 4), 0, stream>>>(x, W, hb);
    k1b_att<<<(N_NODES * 64 + 255) / 256, 256, 0, stream>>>(hb, att_src, att_dst, a_src, a_dst, cnt);
    k_bucket<<<((N_EDGES + 255) / 256) * NXCD, 256, 0, stream>>>(ei, a_src, a_dst, cnt, bkt);
    k_gather<<<((DST_PER_PART + 3) / 4) * NXCD, 256, 0, stream>>>(
        cnt, bkt, a_src, a_dst, hb, bias, out);
}